// Round 7
// baseline (120.427 us; speedup 1.0000x reference)
//
#include <hip/hip_runtime.h>
#include <hip/hip_bf16.h>

#define BB 4
#define TT 2048
#define CC 1024
#define HSZ 64
#define NTOT 8192

typedef __attribute__((ext_vector_type(8))) short bf16x8;
typedef __attribute__((ext_vector_type(4))) float f32x4;

__device__ __forceinline__ unsigned short f2bf(float x) {
    __hip_bfloat16 h = __float2bfloat16(x);
    return *reinterpret_cast<unsigned short*>(&h);
}
__device__ __forceinline__ float bf2f(unsigned short u) {
    return __uint_as_float(((unsigned int)u) << 16);
}

// ---- W -> bf16 hi plane [192][1024]; q-part pre-scaled by HS^-0.5 ----
__global__ __launch_bounds__(256) void convert_w(
    const float* __restrict__ Wq, const float* __restrict__ Wk,
    const float* __restrict__ Wv, unsigned short* __restrict__ Wh) {
    int i = blockIdx.x * 256 + threadIdx.x;
    if (i >= 192 * 1024) return;
    int c = i >> 10, kk = i & 1023;
    float val;
    if (c < 64) val = Wq[(size_t)c * CC + kk] * 0.125f;
    else if (c < 128) val = Wk[(size_t)(c - 64) * CC + kk];
    else val = Wv[(size_t)(c - 128) * CC + kk];
    Wh[i] = f2bf(val);
}

// ---- QKV GEMM, barrier-free: W B-frags straight from L2, K-split 4 over waves ----
// 512 blocks x 256 thr (4 waves). Block = 16 rows; wave w = K range [w*256, w*256+256).
// x hi/lo split in registers for fp32-grade accuracy. LDS only for the final combine.
__global__ __launch_bounds__(256, 2) void qkv_mfma(
    const float* __restrict__ x, const unsigned short* __restrict__ Wh,
    unsigned short* __restrict__ qs, unsigned short* __restrict__ ksb,
    unsigned short* __restrict__ vT) {
    __shared__ __align__(16) float Pt[4 * 16 * 196];  // 50176 B

    const int tid = threadIdx.x;
    const int w = tid >> 6, lane = tid & 63;
    const int l16 = lane & 15, quad = lane >> 4;
    const int row0 = blockIdx.x * 16;
    const int Arow = row0 + l16;

    f32x4 acc[12];
#pragma unroll
    for (int t = 0; t < 12; ++t) acc[t] = (f32x4){0.f, 0.f, 0.f, 0.f};

#pragma unroll
    for (int ch = 0; ch < 4; ++ch) {
        const int kb = w * 256 + ch * 64;
        // A-frags: 16 fp32 per lane, hi/lo split
        const float* xp = x + (size_t)Arow * CC + kb;
        float4 xa = *(const float4*)&xp[quad * 8];
        float4 xb = *(const float4*)&xp[quad * 8 + 4];
        float4 xc = *(const float4*)&xp[32 + quad * 8];
        float4 xd = *(const float4*)&xp[32 + quad * 8 + 4];
        bf16x8 ah0, al0, ah1, al1;
        {
            float v0[8] = {xa.x, xa.y, xa.z, xa.w, xb.x, xb.y, xb.z, xb.w};
            float v1[8] = {xc.x, xc.y, xc.z, xc.w, xd.x, xd.y, xd.z, xd.w};
#pragma unroll
            for (int j = 0; j < 8; ++j) {
                unsigned short h = f2bf(v0[j]);
                ah0[j] = (short)h;
                al0[j] = (short)f2bf(v0[j] - bf2f(h));
                unsigned short h2 = f2bf(v1[j]);
                ah1[j] = (short)h2;
                al1[j] = (short)f2bf(v1[j] - bf2f(h2));
            }
        }
#pragma unroll
        for (int nt = 0; nt < 12; ++nt) {
            const unsigned short* Wp = &Wh[(size_t)(nt * 16 + l16) * CC + kb + quad * 8];
            bf16x8 b0 = *(const bf16x8*)Wp;
            bf16x8 b1 = *(const bf16x8*)(Wp + 32);
            f32x4 a = acc[nt];
            a = __builtin_amdgcn_mfma_f32_16x16x32_bf16(ah0, b0, a, 0, 0, 0);
            a = __builtin_amdgcn_mfma_f32_16x16x32_bf16(al0, b0, a, 0, 0, 0);
            a = __builtin_amdgcn_mfma_f32_16x16x32_bf16(ah1, b1, a, 0, 0, 0);
            a = __builtin_amdgcn_mfma_f32_16x16x32_bf16(al1, b1, a, 0, 0, 0);
            acc[nt] = a;
        }
    }
    // partials -> LDS
#pragma unroll
    for (int nt = 0; nt < 12; ++nt)
#pragma unroll
        for (int r = 0; r < 4; ++r)
            Pt[(w * 16 + quad * 4 + r) * 196 + nt * 16 + l16] = acc[nt][r];
    __syncthreads();
    // combine 4 K-split partials, convert, store
    for (int e = tid; e < 16 * 192; e += 256) {
        const int row = e / 192, col = e - row * 192;
        float s = 0.f;
#pragma unroll
        for (int kk = 0; kk < 4; ++kk) s += Pt[(kk * 16 + row) * 196 + col];
        unsigned short h = f2bf(s);
        const int grow = row0 + row;
        if (col < 64) qs[(size_t)grow * HSZ + col] = h;
        else if (col < 128) ksb[(size_t)grow * HSZ + (col - 64)] = h;
        else vT[(size_t)(col - 128) * NTOT + grow] = h;
    }
}

// ---- Flash attention, fixed-max streaming softmax, K-prefetch pipeline ----
// 512 blocks x 256 thr (4 waves). 16 q-rows/block; waves split key-tiles of 64.
// No barriers / cross-lane in the loop; V loads issued at top; next K prefetched.
__global__ __launch_bounds__(256, 2) void attn_mfma(
    const unsigned short* __restrict__ qs, const unsigned short* __restrict__ ksb,
    const unsigned short* __restrict__ vT, float* __restrict__ out) {
    __shared__ __align__(16) unsigned char smem[17664];
    unsigned short* Ps = (unsigned short*)smem;   // [4][16*72] = 9216 B
    float* Om = (float*)smem;                     // [4][16][68] = 17408 B (after barrier)
    float* Lm = (float*)(smem + 17408);           // [4][16] = 256 B

    const int raw = blockIdx.x;
    const int i = (raw < 256) ? raw : 767 - raw;  // pair long+short causal tiles per CU
    const int b = i >> 7;
    const int qt = i & 127;
    const int t0 = qt * 16;
    const int tid = threadIdx.x;
    const int w = tid >> 6, lane = tid & 63;
    const int l16 = lane & 15, quad = lane >> 4;

    const size_t qoff = (size_t)(b * TT + t0 + l16) * HSZ + quad * 8;
    const bf16x8 aq0 = *(const bf16x8*)&qs[qoff];
    const bf16x8 aq1 = *(const bf16x8*)&qs[qoff + 32];

    f32x4 OC[4];
#pragma unroll
    for (int t = 0; t < 4; ++t) OC[t] = (f32x4){0.f, 0.f, 0.f, 0.f};
    float lsum[4] = {0.f, 0.f, 0.f, 0.f};

    const unsigned short* kbase = ksb + (size_t)b * TT * HSZ;
    const int nk = (qt >> 2) + 1;

    // prefetch first K tile for this wave
    bf16x8 ck0[4], ck1[4];
    if (w < nk) {
        const int key0 = w * 64;
#pragma unroll
        for (int nt = 0; nt < 4; ++nt) {
            const unsigned short* kp = kbase + (size_t)(key0 + nt * 16 + l16) * HSZ + quad * 8;
            ck0[nt] = *(const bf16x8*)kp;
            ck1[nt] = *(const bf16x8*)(kp + 32);
        }
    }

    for (int j = w; j < nk; j += 4) {
        const int key0 = j * 64;
        // V loads for current tile (latency hidden behind QK+exp+LDS chain)
        bf16x8 cv0[4], cv1[4];
#pragma unroll
        for (int ht = 0; ht < 4; ++ht) {
            const unsigned short* vp = vT + (size_t)(ht * 16 + l16) * NTOT + b * TT + key0 + quad * 8;
            cv0[ht] = *(const bf16x8*)vp;
            cv1[ht] = *(const bf16x8*)(vp + 32);
        }
        // prefetch next K tile
        bf16x8 nk0[4], nk1[4];
        const bool more = (j + 4) < nk;
        if (more) {
            const int key0n = key0 + 256;
#pragma unroll
            for (int nt = 0; nt < 4; ++nt) {
                const unsigned short* kp = kbase + (size_t)(key0n + nt * 16 + l16) * HSZ + quad * 8;
                nk0[nt] = *(const bf16x8*)kp;
                nk1[nt] = *(const bf16x8*)(kp + 32);
            }
        }
        // QK^T
        f32x4 S[4];
#pragma unroll
        for (int nt = 0; nt < 4; ++nt) {
            f32x4 a = (f32x4){0.f, 0.f, 0.f, 0.f};
            a = __builtin_amdgcn_mfma_f32_16x16x32_bf16(aq0, ck0[nt], a, 0, 0, 0);
            a = __builtin_amdgcn_mfma_f32_16x16x32_bf16(aq1, ck1[nt], a, 0, 0, 0);
            S[nt] = a;
        }
        if (j == nk - 1) {  // causal mask on the diagonal tile
#pragma unroll
            for (int nt = 0; nt < 4; ++nt) {
                const int key = key0 + nt * 16 + l16;
#pragma unroll
                for (int r = 0; r < 4; ++r)
                    if (key > t0 + quad * 4 + r) S[nt][r] = -1e30f;
            }
        }
        // P = exp(S); per-lane row-sum partials
#pragma unroll
        for (int nt = 0; nt < 4; ++nt)
#pragma unroll
            for (int r = 0; r < 4; ++r) S[nt][r] = __expf(S[nt][r]);
#pragma unroll
        for (int r = 0; r < 4; ++r)
            lsum[r] += S[0][r] + S[1][r] + S[2][r] + S[3][r];
        // P: C-layout -> wave-private LDS -> A-layout
        unsigned short* Pw = Ps + w * 1152;
#pragma unroll
        for (int nt = 0; nt < 4; ++nt)
#pragma unroll
            for (int r = 0; r < 4; ++r)
                Pw[(quad * 4 + r) * 72 + nt * 16 + l16] = f2bf(S[nt][r]);
        bf16x8 pf0 = *(const bf16x8*)&Pw[l16 * 72 + quad * 8];
        bf16x8 pf1 = *(const bf16x8*)&Pw[l16 * 72 + 32 + quad * 8];
        // PV
#pragma unroll
        for (int ht = 0; ht < 4; ++ht) {
            f32x4 a = OC[ht];
            a = __builtin_amdgcn_mfma_f32_16x16x32_bf16(pf0, cv0[ht], a, 0, 0, 0);
            a = __builtin_amdgcn_mfma_f32_16x16x32_bf16(pf1, cv1[ht], a, 0, 0, 0);
            OC[ht] = a;
        }
        if (more) {
#pragma unroll
            for (int nt = 0; nt < 4; ++nt) { ck0[nt] = nk0[nt]; ck1[nt] = nk1[nt]; }
        }
    }
    // reduce lsum across the 16 lanes holding each row's columns
#pragma unroll
    for (int r = 0; r < 4; ++r) {
        float v = lsum[r];
#pragma unroll
        for (int off = 1; off < 16; off <<= 1) v += __shfl_xor(v, off, 64);
        lsum[r] = v;
    }
    __syncthreads();  // everyone done with Ps; reuse as Om
#pragma unroll
    for (int ht = 0; ht < 4; ++ht)
#pragma unroll
        for (int r = 0; r < 4; ++r)
            Om[(w * 16 + quad * 4 + r) * 68 + ht * 16 + l16] = OC[ht][r];
    if (l16 == 0) {
#pragma unroll
        for (int r = 0; r < 4; ++r) Lm[w * 16 + quad * 4 + r] = lsum[r];
    }
    __syncthreads();
    // merge 4 waves (plain sums) and write
    {
        const int row = tid >> 4, h0 = (tid & 15) * 4;
        float L = 0.f, o0 = 0.f, o1 = 0.f, o2 = 0.f, o3 = 0.f;
#pragma unroll
        for (int w2 = 0; w2 < 4; ++w2) {
            L += Lm[w2 * 16 + row];
            const float* p = &Om[(w2 * 16 + row) * 68 + h0];
            o0 += p[0]; o1 += p[1]; o2 += p[2]; o3 += p[3];
        }
        const float inv = 1.f / L;
        *(float4*)&out[(size_t)(b * TT + t0 + row) * HSZ + h0] =
            (float4){o0 * inv, o1 * inv, o2 * inv, o3 * inv};
    }
}

extern "C" void kernel_launch(void* const* d_in, const int* in_sizes, int n_in,
                              void* d_out, int out_size, void* d_ws, size_t ws_size,
                              hipStream_t stream) {
    const float* x  = (const float*)d_in[0];
    const float* Wq = (const float*)d_in[1];
    const float* Wk = (const float*)d_in[2];
    const float* Wv = (const float*)d_in[3];
    float* out = (float*)d_out;

    unsigned short* qs = (unsigned short*)d_ws;
    unsigned short* ksb = qs + (size_t)NTOT * HSZ;
    unsigned short* vT = ksb + (size_t)NTOT * HSZ;
    unsigned short* Wh = vT + (size_t)NTOT * HSZ;  // 192*1024

    convert_w<<<768, 256, 0, stream>>>(Wq, Wk, Wv, Wh);
    qkv_mfma<<<512, 256, 0, stream>>>(x, Wh, qs, ksb, vT);
    attn_mfma<<<512, 256, 0, stream>>>(qs, ksb, vT, out);
}